// Round 1
// baseline (112.632 us; speedup 1.0000x reference)
//
#include <hip/hip_runtime.h>

// Backwarp (tfa.image.dense_image_warp):
// out[b,y,x,c] = bilinear(image, y - flow[b,y,x,0], x - flow[b,y,x,1])
// floors clamped to [0, size-2], alphas clamped to [0,1].

#define BB 4
#define HH 512
#define WW 512
#define CC 64
#define CV (CC / 4)   // 16 float4 chunks per pixel

__global__ __launch_bounds__(256) void backwarp_kernel(
    const float* __restrict__ image,
    const float* __restrict__ flow,
    float* __restrict__ out)
{
    // idx = ((b*H + y)*W + x)*CV + cv
    long long idx = (long long)blockIdx.x * 256 + threadIdx.x;
    int cv = (int)(idx & (CV - 1));
    long long p = idx >> 4;              // pixel index b*H*W + y*W + x
    int x = (int)(p & (WW - 1));
    long long t = p >> 9;
    int y = (int)(t & (HH - 1));
    int b = (int)(t >> 9);

    // flow for this pixel (same addr across the 16-lane group -> broadcast)
    float2 fl = ((const float2*)flow)[p];
    float qy = (float)y - fl.x;
    float qx = (float)x - fl.y;

    float fy = fminf(fmaxf(floorf(qy), 0.0f), (float)(HH - 2));
    float fx = fminf(fmaxf(floorf(qx), 0.0f), (float)(WW - 2));
    float ay = fminf(fmaxf(qy - fy, 0.0f), 1.0f);
    float ax = fminf(fmaxf(qx - fx, 0.0f), 1.0f);
    int y0 = (int)fy;
    int x0 = (int)fx;

    const float4* img4 = (const float4*)image;
    long long i00 = (((long long)b * HH + y0) * WW + x0) * CV + cv;
    long long i01 = i00 + CV;              // x0+1
    long long i10 = i00 + (long long)WW * CV;  // y0+1
    long long i11 = i10 + CV;

    float4 tl = img4[i00];
    float4 tr = img4[i01];
    float4 bl = img4[i10];
    float4 br = img4[i11];

    float4 r;
    {
        float top, bot;
        top = tl.x + ax * (tr.x - tl.x);
        bot = bl.x + ax * (br.x - bl.x);
        r.x = top + ay * (bot - top);
        top = tl.y + ax * (tr.y - tl.y);
        bot = bl.y + ax * (br.y - bl.y);
        r.y = top + ay * (bot - top);
        top = tl.z + ax * (tr.z - tl.z);
        bot = bl.z + ax * (br.z - bl.z);
        r.z = top + ay * (bot - top);
        top = tl.w + ax * (tr.w - tl.w);
        bot = bl.w + ax * (br.w - bl.w);
        r.w = top + ay * (bot - top);
    }

    ((float4*)out)[idx] = r;
}

extern "C" void kernel_launch(void* const* d_in, const int* in_sizes, int n_in,
                              void* d_out, int out_size, void* d_ws, size_t ws_size,
                              hipStream_t stream) {
    const float* image = (const float*)d_in[0];
    const float* flow  = (const float*)d_in[1];
    float* out = (float*)d_out;

    const long long total = (long long)BB * HH * WW * CV;  // 16,777,216 threads
    const int block = 256;
    const long long grid = total / block;                  // 65,536 blocks, no tail

    backwarp_kernel<<<(unsigned)grid, block, 0, stream>>>(image, flow, out);
}

// Round 3
// 107.596 us; speedup vs baseline: 1.0468x; 1.0468x over previous
//
#include <hip/hip_runtime.h>

// Backwarp (tfa.image.dense_image_warp):
// out[b,y,x,c] = bilinear(image, y - flow[b,y,x,0], x - flow[b,y,x,1])
// floors clamped to [0, size-2], alphas clamped to [0,1].

#define BB 4
#define HH 512
#define WW 512
#define CC 64
#define CV (CC / 4)   // 16 float4 chunks per pixel
#define CT 8          // 8 threads per pixel, 2 float4 chunks each

typedef float f32x4 __attribute__((ext_vector_type(4)));

__global__ __launch_bounds__(256) void backwarp_kernel(
    const float* __restrict__ image,
    const float* __restrict__ flow,
    float* __restrict__ out)
{
    // idx = pixel*CT + c8 ; thread handles chunks c8 and c8+8
    long long idx = (long long)blockIdx.x * 256 + threadIdx.x;
    int c8 = (int)(idx & (CT - 1));
    long long p = idx >> 3;              // pixel index b*H*W + y*W + x
    int x = (int)(p & (WW - 1));
    long long t = p >> 9;
    int y = (int)(t & (HH - 1));
    int b = (int)(t >> 9);

    // flow for this pixel (8 lanes share -> single cache line per pixel)
    float2 fl = ((const float2*)flow)[p];
    float qy = (float)y - fl.x;
    float qx = (float)x - fl.y;

    float fy = fminf(fmaxf(floorf(qy), 0.0f), (float)(HH - 2));
    float fx = fminf(fmaxf(floorf(qx), 0.0f), (float)(WW - 2));
    float ay = fminf(fmaxf(qy - fy, 0.0f), 1.0f);
    float ax = fminf(fmaxf(qx - fx, 0.0f), 1.0f);
    int y0 = (int)fy;
    int x0 = (int)fx;

    const f32x4* img4 = (const f32x4*)image;
    long long i00 = (((long long)b * HH + y0) * WW + x0) * CV + c8;
    long long i01 = i00 + CV;                  // x0+1
    long long i10 = i00 + (long long)WW * CV;  // y0+1
    long long i11 = i10 + CV;

    // chunk A (c8) and chunk B (c8+8) — B is +128 bytes, folds to imm offset
    f32x4 tlA = img4[i00];     f32x4 tlB = img4[i00 + 8];
    f32x4 trA = img4[i01];     f32x4 trB = img4[i01 + 8];
    f32x4 blA = img4[i10];     f32x4 blB = img4[i10 + 8];
    f32x4 brA = img4[i11];     f32x4 brB = img4[i11 + 8];

    // bilinear lerp, vectorized over the 4 channels of each chunk
    f32x4 topA = tlA + ax * (trA - tlA);
    f32x4 botA = blA + ax * (brA - blA);
    f32x4 rA   = topA + ay * (botA - topA);
    f32x4 topB = tlB + ax * (trB - tlB);
    f32x4 botB = blB + ax * (brB - blB);
    f32x4 rB   = topB + ay * (botB - topB);

    // output is write-once, never re-read: bypass L2 so image gather lines survive
    long long o = p * CV + c8;
    f32x4* out4 = (f32x4*)out;
    __builtin_nontemporal_store(rA, &out4[o]);
    __builtin_nontemporal_store(rB, &out4[o + 8]);
}

extern "C" void kernel_launch(void* const* d_in, const int* in_sizes, int n_in,
                              void* d_out, int out_size, void* d_ws, size_t ws_size,
                              hipStream_t stream) {
    const float* image = (const float*)d_in[0];
    const float* flow  = (const float*)d_in[1];
    float* out = (float*)d_out;

    const long long total = (long long)BB * HH * WW * CT;  // 8,388,608 threads
    const int block = 256;
    const long long grid = total / block;                  // 32,768 blocks, no tail

    backwarp_kernel<<<(unsigned)grid, block, 0, stream>>>(image, flow, out);
}

// Round 4
// 101.745 us; speedup vs baseline: 1.1070x; 1.0575x over previous
//
#include <hip/hip_runtime.h>

// Backwarp (tfa.image.dense_image_warp):
// out[b,y,x,c] = bilinear(image, y - flow[b,y,x,0], x - flow[b,y,x,1])
// floors clamped to [0, size-2], alphas clamped to [0,1].

#define BB 4
#define HH 512
#define WW 512
#define CV 16        // float4 chunks per pixel (C=64)
#define NBLK 16384   // blocks; each covers 64 consecutive pixels (2 iters x 32)

typedef float f32x4 __attribute__((ext_vector_type(4)));
typedef float f32x2 __attribute__((ext_vector_type(2)));

__device__ __forceinline__ void warp_body(
    const f32x4* __restrict__ img4, f32x4* __restrict__ out4,
    long long p, int c8, f32x2 fl)
{
    int x = (int)(p & (WW - 1));
    long long t = p >> 9;
    int y = (int)(t & (HH - 1));
    int b = (int)(t >> 9);

    float qy = (float)y - fl.x;
    float qx = (float)x - fl.y;
    float fy = fminf(fmaxf(floorf(qy), 0.0f), (float)(HH - 2));
    float fx = fminf(fmaxf(floorf(qx), 0.0f), (float)(WW - 2));
    float ay = fminf(fmaxf(qy - fy, 0.0f), 1.0f);
    float ax = fminf(fmaxf(qx - fx, 0.0f), 1.0f);
    int y0 = (int)fy;
    int x0 = (int)fx;

    long long i00 = (((long long)b * HH + y0) * WW + x0) * CV + c8;
    long long i01 = i00 + CV;                  // x0+1
    long long i10 = i00 + (long long)WW * CV;  // y0+1
    long long i11 = i10 + CV;

    f32x4 tlA = img4[i00];  f32x4 tlB = img4[i00 + 8];
    f32x4 trA = img4[i01];  f32x4 trB = img4[i01 + 8];
    f32x4 blA = img4[i10];  f32x4 blB = img4[i10 + 8];
    f32x4 brA = img4[i11];  f32x4 brB = img4[i11 + 8];

    f32x4 topA = tlA + ax * (trA - tlA);
    f32x4 botA = blA + ax * (brA - blA);
    f32x4 rA   = topA + ay * (botA - topA);
    f32x4 topB = tlB + ax * (trB - tlB);
    f32x4 botB = blB + ax * (brB - blB);
    f32x4 rB   = topB + ay * (botB - topB);

    long long o = p * CV + c8;
    __builtin_nontemporal_store(rA, &out4[o]);      // write-once: bypass L2
    __builtin_nontemporal_store(rB, &out4[o + 8]);
}

__global__ __launch_bounds__(256) void backwarp_kernel(
    const float* __restrict__ image,
    const float* __restrict__ flow,
    float* __restrict__ out)
{
    // XCD-bijective swizzle: each XCD gets a contiguous 1/8 slab of the grid
    int bid = (int)blockIdx.x;
    int orig = (bid & 7) * (NBLK / 8) + (bid >> 3);

    long long pix_base = (long long)orig * 64;
    int c8 = (int)(threadIdx.x & 7);   // which pair of float4 chunks
    int pl = (int)(threadIdx.x >> 3);  // pixel lane 0..31
    long long p0 = pix_base + pl;
    long long p1 = pix_base + 32 + pl;

    // both flow loads issued up front: iter-1's flow latency hides under iter-0
    const f32x2* flow2 = (const f32x2*)flow;
    f32x2 fl0 = __builtin_nontemporal_load(&flow2[p0]);
    f32x2 fl1 = __builtin_nontemporal_load(&flow2[p1]);

    const f32x4* img4 = (const f32x4*)image;
    f32x4* out4 = (f32x4*)out;

    warp_body(img4, out4, p0, c8, fl0);
    warp_body(img4, out4, p1, c8, fl1);
}

extern "C" void kernel_launch(void* const* d_in, const int* in_sizes, int n_in,
                              void* d_out, int out_size, void* d_ws, size_t ws_size,
                              hipStream_t stream) {
    const float* image = (const float*)d_in[0];
    const float* flow  = (const float*)d_in[1];
    float* out = (float*)d_out;

    backwarp_kernel<<<NBLK, 256, 0, stream>>>(image, flow, out);
}